// Round 1
// 1227.967 us; speedup vs baseline: 1.1944x; 1.1944x over previous
//
#include <hip/hip_runtime.h>
#include <stdint.h>

// CompressedLinear: C[8192,11008] = x[8192,4096] @ (w_int8*scale)[11008,4096]^T + bias
// v2: 256x256 tile, BK=32, 4-deep LDS ring with counted vmcnt(12) (T3/T4),
//     XOR-swizzled LDS (T2, both-sides-or-neither), setprio (T5), XCD swizzle (T1),
//     fused conversion kernel.

#define M_DIM 8192
#define N_DIM 11008
#define K_DIM 4096

#define BM 256
#define BN 256
#define BK 32
#define NT (K_DIM / BK)      // 128 K-tiles
#define NBN (N_DIM / BN)     // 43
#define NBM (M_DIM / BM)     // 32
#define GRID (NBM * NBN)     // 1376 = 8 * 172  (nwg % 8 == 0, bijective XCD swizzle)

typedef short bf16x8 __attribute__((ext_vector_type(8)));   // 8 bf16 = 4 VGPRs
typedef float f32x4 __attribute__((ext_vector_type(4)));

__device__ __forceinline__ unsigned short f2bf(float f) {
    union { float f; uint32_t u; } c; c.f = f;
    uint32_t u = c.u;
    return (unsigned short)((u + 0x7FFFu + ((u >> 16) & 1u)) >> 16);  // RNE, no NaN inputs
}

// Fused x(fp32)->bf16 and w(int32)->bf16 conversion, grid-stride (G11/G13).
__global__ __launch_bounds__(256) void cvt_fused_kernel(
    const float* __restrict__ x, const int* __restrict__ w,
    unsigned short* __restrict__ xo, unsigned short* __restrict__ wo)
{
    const int NX4 = M_DIM * K_DIM / 4;   // 8,388,608
    const int NW4 = N_DIM * K_DIM / 4;   // 11,272,192
    const int stride = gridDim.x * blockDim.x;
    const int t0 = blockIdx.x * blockDim.x + threadIdx.x;
    for (int i = t0; i < NX4; i += stride) {
        float4 v = ((const float4*)x)[i];
        ushort4 r;
        r.x = f2bf(v.x); r.y = f2bf(v.y); r.z = f2bf(v.z); r.w = f2bf(v.w);
        ((ushort4*)xo)[i] = r;
    }
    for (int i = t0; i < NW4; i += stride) {
        int4 v = ((const int4*)w)[i];
        ushort4 r;  // int8 values are exact in bf16
        r.x = f2bf((float)v.x); r.y = f2bf((float)v.y);
        r.z = f2bf((float)v.z); r.w = f2bf((float)v.w);
        ((ushort4*)wo)[i] = r;
    }
}

// async 16B global->LDS; LDS dest is wave-uniform base + lane*16 (m104) — our
// per-thread t*16 pattern satisfies this. Global source IS per-lane (m173),
// which is how the inverse swizzle is applied.
__device__ __forceinline__ void async16(const void* g, void* l) {
    __builtin_amdgcn_global_load_lds((__attribute__((address_space(1))) void*)g,
                                     (__attribute__((address_space(3))) void*)l,
                                     16, 0, 0);
}

// LDS swizzle: within a 64B row (BK=32 bf16), 16B slot s of row r holds global
// slot s ^ ((r>>1)&3). Involution; applied to BOTH the global source address at
// stage time (linear LDS dest) and the ds_read address (rule #21).
// Bank check (ds_read_b128, 64 lanes): group = 4*(l16&1) + (quad ^ ((l16>>1)&3))
// -> all 8 16B-groups hit exactly 2x per quad, 8x per wave = conflict-free minimum.

__global__ __launch_bounds__(512, 2) void gemm_bf16_kernel(
    const unsigned short* __restrict__ A,   // [M][K] bf16
    const unsigned short* __restrict__ B,   // [N][K] bf16 (B^T layout)
    const float* __restrict__ scale_p,
    const float* __restrict__ bias,
    float* __restrict__ out)                // [M][N] fp32
{
    // 4-ring: A slots at lds + buf*16384 (64KB), B slots at lds + 65536 + buf*16384
    __shared__ __attribute__((aligned(16))) char lds[131072];

    const int t    = threadIdx.x;
    const int lane = t & 63;
    const int w    = t >> 6;       // 0..7
    const int wm   = w >> 2;       // 0..1  (wave owns 128 M-rows)
    const int wn   = w & 3;        // 0..3  (wave owns 64 N-cols)
    const int quad = lane >> 4;
    const int l16  = lane & 15;

    // T1: bijective XCD swizzle; consecutive swz share the A panel (bn fastest)
    const int bid = blockIdx.x;
    const int swz = (bid & 7) * (GRID / 8) + (bid >> 3);
    const int bm = swz / NBN;
    const int bn = swz % NBN;

    f32x4 acc[8][4];
#pragma unroll
    for (int i = 0; i < 8; i++)
#pragma unroll
        for (int j = 0; j < 4; j++)
            acc[i][j] = (f32x4){0.f, 0.f, 0.f, 0.f};

    // --- staging addresses: thread t covers rows (t>>2) and (t>>2)+128, slot t&3.
    // swizzle value identical for r and r+128 (128/2 ≡ 0 mod 4).
    const int rowh = t >> 2;            // 0..127
    const int slot = t & 3;
    const int csw  = ((slot ^ ((rowh >> 1) & 3)) << 4);   // inverse-swizzled col byte
    const char* aS0 = (const char*)(A + (size_t)(bm * BM + rowh) * K_DIM) + csw;
    const char* bS0 = (const char*)(B + (size_t)(bn * BN + rowh) * K_DIM) + csw;
    const char* aS1 = aS0 + (size_t)128 * K_DIM * 2;
    const char* bS1 = bS0 + (size_t)128 * K_DIM * 2;
    char* aD = lds + t * 16;            // linear LDS dest (global_load_lds requirement)
    char* bD = lds + 65536 + t * 16;

#define STAGE(buf, kt) do { \
        const size_t kb_ = (size_t)(kt) * (BK * 2); \
        async16(aS0 + kb_, aD + ((buf) << 14)); \
        async16(aS1 + kb_, aD + ((buf) << 14) + 8192); \
        async16(bS0 + kb_, bD + ((buf) << 14)); \
        async16(bS1 + kb_, bD + ((buf) << 14) + 8192); \
    } while (0)

    // prologue: tiles 0,1,2 in flight (12 loads/wave)
    STAGE(0, 0); STAGE(1, 1); STAGE(2, 2);

    // --- ds_read fragment addresses. (row>>1)&3 reduces to (l16>>1)&3 for all
    // frag bases (bases are multiples of 16), so the swizzled col offset is a
    // per-thread constant:
    const int coff = ((quad ^ ((l16 >> 1) & 3)) << 4);
    const int aoff = (wm * 128 + l16) * (BK * 2) + coff;
    const int boff = 65536 + (wn * 64 + l16) * (BK * 2) + coff;

#pragma unroll 4
    for (int kt = 0; kt < NT; kt++) {
        // stage tile kt+3 into ring slot (kt+3)&3 — its previous contents (tile
        // kt-1) were fully read last iter, protected by the end-of-iter barrier.
        // Tail wraps source index: harmless overwrite of a dead slot, keeps
        // vmcnt arithmetic constant.
        STAGE((kt + 3) & 3, (kt + 3) & (NT - 1));

        // T4: counted wait — 16 loads outstanding, keep 12 (tiles kt+1..kt+3),
        // tile kt guaranteed landed. Never drains in the main loop.
        asm volatile("s_waitcnt vmcnt(12)" ::: "memory");
        __builtin_amdgcn_s_barrier();           // all waves' tile-kt loads landed
        asm volatile("" ::: "memory");          // no LDS read may float above the barrier

        const char* Ab = lds + ((kt & 3) << 14) + aoff;
        const char* Bb = lds + ((kt & 3) << 14) + boff;

        bf16x8 bfr[4], afr[4];
#pragma unroll
        for (int j = 0; j < 4; j++)
            bfr[j] = *(const bf16x8*)(Bb + j * 1024);
#pragma unroll
        for (int i = 0; i < 4; i++)
            afr[i] = *(const bf16x8*)(Ab + i * 1024);

        __builtin_amdgcn_s_setprio(1);          // T5
#pragma unroll
        for (int i = 0; i < 4; i++)
#pragma unroll
            for (int j = 0; j < 4; j++)
                acc[i][j] = __builtin_amdgcn_mfma_f32_16x16x32_bf16(
                    afr[i], bfr[j], acc[i][j], 0, 0, 0);
        __builtin_amdgcn_s_setprio(0);

#pragma unroll
        for (int i = 0; i < 4; i++)
            afr[i] = *(const bf16x8*)(Ab + (i + 4) * 1024);

        __builtin_amdgcn_s_setprio(1);
#pragma unroll
        for (int i = 0; i < 4; i++)
#pragma unroll
            for (int j = 0; j < 4; j++)
                acc[i + 4][j] = __builtin_amdgcn_mfma_f32_16x16x32_bf16(
                    afr[i], bfr[j], acc[i + 4][j], 0, 0, 0);
        __builtin_amdgcn_s_setprio(0);

        // my ds_reads complete before I signal — next iter's stage may overwrite
        asm volatile("s_waitcnt lgkmcnt(0)" ::: "memory");
        __builtin_amdgcn_s_barrier();
    }
#undef STAGE

    // epilogue: C/D mapping col=lane&15, row=quad*4+reg (m89-verified, unchanged)
    const float scale = *scale_p;
    const int gcol = bn * BN + wn * 64 + l16;
    float bvals[4];
#pragma unroll
    for (int j = 0; j < 4; j++) bvals[j] = bias[gcol + j * 16];

#pragma unroll
    for (int i = 0; i < 8; i++) {
        const int grow0 = bm * BM + wm * 128 + i * 16 + quad * 4;
#pragma unroll
        for (int r = 0; r < 4; r++) {
            float* orow = out + (size_t)(grow0 + r) * N_DIM + gcol;
#pragma unroll
            for (int j = 0; j < 4; j++)
                orow[j * 16] = acc[i][j][r] * scale + bvals[j];
        }
    }
}

// correctness fallback if ws is too small (should not trigger: needs ~157 MB)
__global__ __launch_bounds__(256) void naive_kernel(
    const float* __restrict__ x, const int* __restrict__ w8,
    const float* __restrict__ scale_p, const float* __restrict__ bias,
    float* __restrict__ out)
{
    size_t idx = (size_t)blockIdx.x * 256 + threadIdx.x;
    if (idx >= (size_t)M_DIM * N_DIM) return;
    int n = (int)(idx % N_DIM);
    size_t m = idx / N_DIM;
    const float* xr = x + m * K_DIM;
    const int* wr = w8 + (size_t)n * K_DIM;
    float acc = 0.f;
    for (int k = 0; k < K_DIM; k++) acc += xr[k] * (float)wr[k];
    out[idx] = acc * (*scale_p) + bias[n];
}

extern "C" void kernel_launch(void* const* d_in, const int* in_sizes, int n_in,
                              void* d_out, int out_size, void* d_ws, size_t ws_size,
                              hipStream_t stream) {
    const float* x     = (const float*)d_in[0];
    const int*   w8    = (const int*)d_in[1];
    const float* scale = (const float*)d_in[2];
    const float* bias  = (const float*)d_in[3];
    float* out = (float*)d_out;

    const size_t a_bytes = (size_t)M_DIM * K_DIM * 2;   // 67,108,864
    const size_t b_bytes = (size_t)N_DIM * K_DIM * 2;   // 90,177,536

    if (ws_size >= a_bytes + b_bytes) {
        unsigned short* a_bf = (unsigned short*)d_ws;
        unsigned short* b_bf = (unsigned short*)((char*)d_ws + a_bytes);
        cvt_fused_kernel<<<2048, 256, 0, stream>>>(x, w8, a_bf, b_bf);
        gemm_bf16_kernel<<<GRID, 512, 0, stream>>>(a_bf, b_bf, scale, bias, out);
    } else {
        size_t total = (size_t)M_DIM * N_DIM;
        naive_kernel<<<(unsigned)((total + 255) / 256), 256, 0, stream>>>(
            x, w8, scale, bias, out);
    }
}

// Round 3
// 1181.949 us; speedup vs baseline: 1.2409x; 1.0389x over previous
//
#include <hip/hip_runtime.h>
#include <stdint.h>

// CompressedLinear: C[8192,11008] = x[8192,4096] @ (w_int8*scale)[11008,4096]^T + bias
// v3b: v2 + fragment ping-pong: tile kt+1's ds_reads issue under tile kt's MFMA
//      cluster (ring depth 4 makes kt+1 LDS-resident during iter kt). One barrier
//      per iter, no lgkmcnt drain, vmcnt(8) counted wait.
//      (v3 fix: nontemporal loads via ext_vector_type, not HIP_vector_type)

#define M_DIM 8192
#define N_DIM 11008
#define K_DIM 4096

#define BM 256
#define BN 256
#define BK 32
#define NT (K_DIM / BK)      // 128 K-tiles
#define NBN (N_DIM / BN)     // 43
#define NBM (M_DIM / BM)     // 32
#define GRID (NBM * NBN)     // 1376 = 8 * 172  (nwg % 8 == 0, bijective XCD swizzle)

typedef short bf16x8 __attribute__((ext_vector_type(8)));   // 8 bf16 = 4 VGPRs
typedef float f32x4 __attribute__((ext_vector_type(4)));
typedef float fvec4 __attribute__((ext_vector_type(4)));    // for nontemporal builtin
typedef int   ivec4 __attribute__((ext_vector_type(4)));
typedef unsigned short usvec4 __attribute__((ext_vector_type(4)));

__device__ __forceinline__ unsigned short f2bf(float f) {
    union { float f; uint32_t u; } c; c.f = f;
    uint32_t u = c.u;
    return (unsigned short)((u + 0x7FFFu + ((u >> 16) & 1u)) >> 16);  // RNE, no NaN inputs
}

// Fused x(fp32)->bf16 and w(int32)->bf16 conversion, grid-stride (G11/G13).
// Inputs are read-once -> nontemporal loads; outputs stay cached (gemm reads them).
__global__ __launch_bounds__(256) void cvt_fused_kernel(
    const float* __restrict__ x, const int* __restrict__ w,
    unsigned short* __restrict__ xo, unsigned short* __restrict__ wo)
{
    const int NX4 = M_DIM * K_DIM / 4;   // 8,388,608
    const int NW4 = N_DIM * K_DIM / 4;   // 11,272,192
    const int stride = gridDim.x * blockDim.x;
    const int t0 = blockIdx.x * blockDim.x + threadIdx.x;
    for (int i = t0; i < NX4; i += stride) {
        fvec4 v = __builtin_nontemporal_load(&((const fvec4*)x)[i]);
        usvec4 r;
        r.x = f2bf(v.x); r.y = f2bf(v.y); r.z = f2bf(v.z); r.w = f2bf(v.w);
        ((usvec4*)xo)[i] = r;
    }
    for (int i = t0; i < NW4; i += stride) {
        ivec4 v = __builtin_nontemporal_load(&((const ivec4*)w)[i]);
        usvec4 r;  // int8 values are exact in bf16
        r.x = f2bf((float)v.x); r.y = f2bf((float)v.y);
        r.z = f2bf((float)v.z); r.w = f2bf((float)v.w);
        ((usvec4*)wo)[i] = r;
    }
}

// async 16B global->LDS; LDS dest is wave-uniform base + lane*16 (m104).
// Global source IS per-lane (m173) — carries the inverse swizzle.
__device__ __forceinline__ void async16(const void* g, void* l) {
    __builtin_amdgcn_global_load_lds((__attribute__((address_space(1))) void*)g,
                                     (__attribute__((address_space(3))) void*)l,
                                     16, 0, 0);
}

// LDS swizzle (unchanged from v2, measured 0 conflicts): within a 64B row
// (BK=32 bf16), 16B slot s of row r holds global slot s ^ ((r>>1)&3).
// Applied to BOTH the global source at stage time and the ds_read address.

__global__ __launch_bounds__(512, 2) void gemm_bf16_kernel(
    const unsigned short* __restrict__ A,   // [M][K] bf16
    const unsigned short* __restrict__ B,   // [N][K] bf16 (B^T layout)
    const float* __restrict__ scale_p,
    const float* __restrict__ bias,
    float* __restrict__ out)                // [M][N] fp32
{
    // 4-ring: A slots at lds + buf*16384, B slots at lds + 65536 + buf*16384
    __shared__ __attribute__((aligned(16))) char lds[131072];

    const int t    = threadIdx.x;
    const int lane = t & 63;
    const int w    = t >> 6;       // 0..7
    const int wm   = w >> 2;       // 0..1  (wave owns 128 M-rows)
    const int wn   = w & 3;        // 0..3  (wave owns 64 N-cols)
    const int quad = lane >> 4;
    const int l16  = lane & 15;

    // T1: bijective XCD swizzle (GRID % 8 == 0)
    const int bid = blockIdx.x;
    const int swz = (bid & 7) * (GRID / 8) + (bid >> 3);
    const int bm = swz / NBN;
    const int bn = swz % NBN;

    f32x4 acc[8][4];
#pragma unroll
    for (int i = 0; i < 8; i++)
#pragma unroll
        for (int j = 0; j < 4; j++)
            acc[i][j] = (f32x4){0.f, 0.f, 0.f, 0.f};

    // staging: thread t covers rows (t>>2) and (t>>2)+128, 16B slot t&3.
    const int rowh = t >> 2;            // 0..127
    const int slot = t & 3;
    const int csw  = ((slot ^ ((rowh >> 1) & 3)) << 4);   // inverse-swizzled col byte
    const char* aS0 = (const char*)(A + (size_t)(bm * BM + rowh) * K_DIM) + csw;
    const char* bS0 = (const char*)(B + (size_t)(bn * BN + rowh) * K_DIM) + csw;
    const char* aS1 = aS0 + (size_t)128 * K_DIM * 2;
    const char* bS1 = bS0 + (size_t)128 * K_DIM * 2;
    char* aD = lds + t * 16;            // linear LDS dest (global_load_lds requirement)
    char* bD = lds + 65536 + t * 16;

#define STAGE(buf, kt) do { \
        const size_t kb_ = (size_t)(kt) * (BK * 2); \
        async16(aS0 + kb_, aD + ((buf) << 14)); \
        async16(aS1 + kb_, aD + ((buf) << 14) + 8192); \
        async16(bS0 + kb_, bD + ((buf) << 14)); \
        async16(bS1 + kb_, bD + ((buf) << 14) + 8192); \
    } while (0)

    // ds_read fragment addressing: swizzled col offset is a per-thread constant
    // ((row>>1)&3 == (l16>>1)&3 for all frag bases, which are multiples of 16).
    const int coff = ((quad ^ ((l16 >> 1) & 3)) << 4);
    const int aoff = (wm * 128 + l16) * (BK * 2) + coff;
    const int boff = 65536 + (wn * 64 + l16) * (BK * 2) + coff;

    bf16x8 fa[8], fb[4], ga[8], gb[4];

    // prologue: tiles 0,1,2 in flight; tile 0 -> registers (set f)
    STAGE(0, 0); STAGE(1, 1); STAGE(2, 2);
    asm volatile("s_waitcnt vmcnt(8)" ::: "memory");   // tile 0 landed (mine)
    __builtin_amdgcn_s_barrier();                      // tile 0 landed (all waves)
    asm volatile("" ::: "memory");
#pragma unroll
    for (int j = 0; j < 4; j++) fb[j] = *(const bf16x8*)(lds + boff + j * 1024);
#pragma unroll
    for (int i = 0; i < 8; i++) fa[i] = *(const bf16x8*)(lds + aoff + i * 1024);

    // Per-iter: stage kt+3 | vmcnt(8) -> kt+1 landed | barrier | ds_read kt+1
    // fragments (overlaps MFMA below via lgkmcnt(12)) | 32 MFMA on kt fragments.
    // WAR on ring slots has 2-barrier slack: reads of slot S in iter kt retire
    // via the compiler's lgkm wait before iter kt+1's MFMAs, which precedes the
    // barrier guarding iter kt+2's STAGE into S.
    auto body = [&](int kt, bf16x8 (&ca)[8], bf16x8 (&cb)[4],
                    bf16x8 (&na)[8], bf16x8 (&nb)[4]) __attribute__((always_inline)) {
        STAGE((kt + 3) & 3, (kt + 3) & (NT - 1));      // tail wraps: dead data, keeps vmcnt uniform
        asm volatile("s_waitcnt vmcnt(8)" ::: "memory");
        __builtin_amdgcn_s_barrier();
        asm volatile("" ::: "memory");                 // no LDS read floats above the barrier

        const char* Abn = lds + (((kt + 1) & 3) << 14) + aoff;
        const char* Bbn = lds + (((kt + 1) & 3) << 14) + boff;
#pragma unroll
        for (int j = 0; j < 4; j++) nb[j] = *(const bf16x8*)(Bbn + j * 1024);
#pragma unroll
        for (int i = 0; i < 8; i++) na[i] = *(const bf16x8*)(Abn + i * 1024);

        __builtin_amdgcn_s_setprio(1);                 // T5
#pragma unroll
        for (int i = 0; i < 8; i++)
#pragma unroll
            for (int j = 0; j < 4; j++)
                acc[i][j] = __builtin_amdgcn_mfma_f32_16x16x32_bf16(
                    ca[i], cb[j], acc[i][j], 0, 0, 0);
        __builtin_amdgcn_s_setprio(0);
    };

    for (int kt = 0; kt < NT; kt += 2) {
        body(kt,     fa, fb, ga, gb);   // compute tile kt,   prefetch kt+1
        body(kt + 1, ga, gb, fa, fb);   // compute tile kt+1, prefetch kt+2
    }
#undef STAGE

    // epilogue: C/D mapping col=lane&15, row=quad*4+reg (m89-verified)
    const float scale = *scale_p;
    const int gcol = bn * BN + wn * 64 + l16;
    float bvals[4];
#pragma unroll
    for (int j = 0; j < 4; j++) bvals[j] = bias[gcol + j * 16];

#pragma unroll
    for (int i = 0; i < 8; i++) {
        const int grow0 = bm * BM + wm * 128 + i * 16 + quad * 4;
#pragma unroll
        for (int r = 0; r < 4; r++) {
            float* orow = out + (size_t)(grow0 + r) * N_DIM + gcol;
#pragma unroll
            for (int j = 0; j < 4; j++)
                orow[j * 16] = acc[i][j][r] * scale + bvals[j];
        }
    }
}

// correctness fallback if ws is too small (should not trigger: needs ~157 MB)
__global__ __launch_bounds__(256) void naive_kernel(
    const float* __restrict__ x, const int* __restrict__ w8,
    const float* __restrict__ scale_p, const float* __restrict__ bias,
    float* __restrict__ out)
{
    size_t idx = (size_t)blockIdx.x * 256 + threadIdx.x;
    if (idx >= (size_t)M_DIM * N_DIM) return;
    int n = (int)(idx % N_DIM);
    size_t m = idx / N_DIM;
    const float* xr = x + m * K_DIM;
    const int* wr = w8 + (size_t)n * K_DIM;
    float acc = 0.f;
    for (int k = 0; k < K_DIM; k++) acc += xr[k] * (float)wr[k];
    out[idx] = acc * (*scale_p) + bias[n];
}

extern "C" void kernel_launch(void* const* d_in, const int* in_sizes, int n_in,
                              void* d_out, int out_size, void* d_ws, size_t ws_size,
                              hipStream_t stream) {
    const float* x     = (const float*)d_in[0];
    const int*   w8    = (const int*)d_in[1];
    const float* scale = (const float*)d_in[2];
    const float* bias  = (const float*)d_in[3];
    float* out = (float*)d_out;

    const size_t a_bytes = (size_t)M_DIM * K_DIM * 2;   // 67,108,864
    const size_t b_bytes = (size_t)N_DIM * K_DIM * 2;   // 90,177,536

    if (ws_size >= a_bytes + b_bytes) {
        unsigned short* a_bf = (unsigned short*)d_ws;
        unsigned short* b_bf = (unsigned short*)((char*)d_ws + a_bytes);
        cvt_fused_kernel<<<2048, 256, 0, stream>>>(x, w8, a_bf, b_bf);
        gemm_bf16_kernel<<<GRID, 512, 0, stream>>>(a_bf, b_bf, scale, bias, out);
    } else {
        size_t total = (size_t)M_DIM * N_DIM;
        naive_kernel<<<(unsigned)((total + 255) / 256), 256, 0, stream>>>(
            x, w8, scale, bias, out);
    }
}

// Round 4
// 1154.372 us; speedup vs baseline: 1.2706x; 1.0239x over previous
//
#include <hip/hip_runtime.h>
#include <stdint.h>

// CompressedLinear: C[8192,11008] = x[8192,4096] @ (w_int8*scale)[11008,4096]^T + bias
// v4: persistent blocks (256, one/CU) walking XCD-chunked tiles; LDS ring + frag
//     ping-pong carried ACROSS tile boundaries (tail stages prefetch next tile);
//     nontemporal C stores (stop L3 eviction of B); STAGE moved after barrier
//     (closes WAR race), vmcnt(4) counted wait (same 2-iter slack).

#define M_DIM 8192
#define N_DIM 11008
#define K_DIM 4096

#define BM 256
#define BN 256
#define BK 32
#define NT (K_DIM / BK)      // 128 K-tiles
#define NBN (N_DIM / BN)     // 43
#define NBM (M_DIM / BM)     // 32
#define GRID (NBM * NBN)     // 1376 = 8 * 172
#define CHUNK (GRID / 8)     // 172 tiles per XCD
#define RS ((size_t)128 * K_DIM * 2)   // +128 rows in bf16 bytes

typedef short bf16x8 __attribute__((ext_vector_type(8)));   // 8 bf16 = 4 VGPRs
typedef float f32x4 __attribute__((ext_vector_type(4)));
typedef float fvec4 __attribute__((ext_vector_type(4)));
typedef int   ivec4 __attribute__((ext_vector_type(4)));
typedef unsigned short usvec4 __attribute__((ext_vector_type(4)));

__device__ __forceinline__ unsigned short f2bf(float f) {
    union { float f; uint32_t u; } c; c.f = f;
    uint32_t u = c.u;
    return (unsigned short)((u + 0x7FFFu + ((u >> 16) & 1u)) >> 16);  // RNE, no NaN inputs
}

// Fused x(fp32)->bf16 and w(int32)->bf16 conversion, grid-stride.
__global__ __launch_bounds__(256) void cvt_fused_kernel(
    const float* __restrict__ x, const int* __restrict__ w,
    unsigned short* __restrict__ xo, unsigned short* __restrict__ wo)
{
    const int NX4 = M_DIM * K_DIM / 4;   // 8,388,608
    const int NW4 = N_DIM * K_DIM / 4;   // 11,272,192
    const int stride = gridDim.x * blockDim.x;
    const int t0 = blockIdx.x * blockDim.x + threadIdx.x;
    for (int i = t0; i < NX4; i += stride) {
        fvec4 v = __builtin_nontemporal_load(&((const fvec4*)x)[i]);
        usvec4 r;
        r.x = f2bf(v.x); r.y = f2bf(v.y); r.z = f2bf(v.z); r.w = f2bf(v.w);
        ((usvec4*)xo)[i] = r;
    }
    for (int i = t0; i < NW4; i += stride) {
        ivec4 v = __builtin_nontemporal_load(&((const ivec4*)w)[i]);
        usvec4 r;  // int8 values are exact in bf16
        r.x = f2bf((float)v.x); r.y = f2bf((float)v.y);
        r.z = f2bf((float)v.z); r.w = f2bf((float)v.w);
        ((usvec4*)wo)[i] = r;
    }
}

// async 16B global->LDS; LDS dest wave-uniform base + lane*16 (m104); global
// source per-lane (m173) — carries the inverse swizzle.
__device__ __forceinline__ void async16(const void* g, void* l) {
    __builtin_amdgcn_global_load_lds((__attribute__((address_space(1))) void*)g,
                                     (__attribute__((address_space(3))) void*)l,
                                     16, 0, 0);
}

// LDS swizzle (v2-proven, 0 conflicts): 16B slot s of row r holds global slot
// s ^ ((r>>1)&3); applied to BOTH stage-source and ds_read (rule #21).

// Per-iteration body:
//   vmcnt(4): tile kt+1 landed (in-order retire; 12 loads out -> retire tile kt, kt+1)
//   barrier : all waves' kt+1 landed; all prior readers of slot (kt+3)&3 drained
//   STAGE   : slot (kt+3)&3 <- K-tile skt from (sa,sb)   [after barrier: no WAR race]
//   ds_read : slot (kt+1)&3 -> (na,nb)  [retires under next iter's MFMA]
//   MFMA    : 32x on (ca,cb)
#define BODY(kt, ca, cb, na, nb, sa, sb, skt) do {                               \
    asm volatile("s_waitcnt vmcnt(4)" ::: "memory");                             \
    __builtin_amdgcn_s_barrier();                                                \
    asm volatile("" ::: "memory");                                               \
    { const int kb_ = (skt) * (BK * 2);                                          \
      const int bo_ = (((kt) + 3) & 3) << 14;                                    \
      async16((sa) + loff + kb_,      aD + bo_);                                 \
      async16((sa) + loff + RS + kb_, aD + bo_ + 8192);                          \
      async16((sb) + loff + kb_,      bD + bo_);                                 \
      async16((sb) + loff + RS + kb_, bD + bo_ + 8192); }                        \
    { const char* Abn_ = lds + ((((kt) + 1) & 3) << 14) + aoff;                  \
      const char* Bbn_ = lds + ((((kt) + 1) & 3) << 14) + boff;                  \
      _Pragma("unroll") for (int j_ = 0; j_ < 4; j_++)                           \
          nb[j_] = *(const bf16x8*)(Bbn_ + j_ * 1024);                           \
      _Pragma("unroll") for (int i_ = 0; i_ < 8; i_++)                           \
          na[i_] = *(const bf16x8*)(Abn_ + i_ * 1024); }                         \
    __builtin_amdgcn_s_setprio(1);                                               \
    _Pragma("unroll") for (int i_ = 0; i_ < 8; i_++)                             \
    _Pragma("unroll") for (int j_ = 0; j_ < 4; j_++)                             \
        acc[i_][j_] = __builtin_amdgcn_mfma_f32_16x16x32_bf16(                   \
            ca[i_], cb[j_], acc[i_][j_], 0, 0, 0);                               \
    __builtin_amdgcn_s_setprio(0);                                               \
} while (0)

__global__ __launch_bounds__(512, 2) void gemm_persistent(
    const unsigned short* __restrict__ A,   // [M][K] bf16
    const unsigned short* __restrict__ B,   // [N][K] bf16 (B^T layout)
    const float* __restrict__ scale_p,
    const float* __restrict__ bias,
    float* __restrict__ out)                // [M][N] fp32
{
    // 4-ring: A slots at lds + buf*16384, B slots at lds + 65536 + buf*16384
    __shared__ __attribute__((aligned(16))) char lds[131072];

    const int t    = threadIdx.x;
    const int lane = t & 63;
    const int w    = t >> 6;       // 0..7
    const int wm   = w >> 2;       // wave row (0..1): 128 M-rows
    const int wn   = w & 3;        // wave col (0..3): 64 N-cols
    const int quad = lane >> 4;
    const int l16  = lane & 15;

    // persistent mapping: CU cu handles tiles xcd*CHUNK + (r*32 + cui), idx < CHUNK.
    // 32 CUs of one XCD work consecutive tiles (same bm -> A-panel hot in its L2).
    const int cu  = blockIdx.x;    // 0..255
    const int xcd = cu & 7;
    const int cui = cu >> 3;       // 0..31

    f32x4 acc[8][4];
#pragma unroll
    for (int i = 0; i < 8; i++)
#pragma unroll
        for (int j = 0; j < 4; j++)
            acc[i][j] = (f32x4){0.f, 0.f, 0.f, 0.f};

    // staging: thread t covers rows (t>>2) and (t>>2)+128, 16B slot t&3;
    // per-lane byte offset (uniform tile base is SGPR, this stays one VGPR).
    const int rowh = t >> 2;
    const int slot = t & 3;
    const int csw  = ((slot ^ ((rowh >> 1) & 3)) << 4);   // inverse-swizzled col
    const size_t loff = (size_t)rowh * K_DIM * 2 + csw;
    char* aD = lds + t * 16;            // linear LDS dest (global_load_lds req.)
    char* bD = lds + 65536 + t * 16;

    // ds_read fragment addressing (per-thread constant swizzled col offset)
    const int coff = ((quad ^ ((l16 >> 1) & 3)) << 4);
    const int aoff = (wm * 128 + l16) * (BK * 2) + coff;
    const int boff = 65536 + (wn * 64 + l16) * (BK * 2) + coff;

    const float scale = *scale_p;

    bf16x8 fa[8], fb[4], ga[8], gb[4];

    // ---- first tile + prologue
    int idx  = cui;
    int tile = xcd * CHUNK + idx;
    int bm = tile / NBN, bn = tile - bm * NBN;
    const char* aCb = (const char*)A + (size_t)bm * BM * K_DIM * 2;
    const char* bCb = (const char*)B + (size_t)bn * BN * K_DIM * 2;

#define STAGE0(ab, bb, buf, kt) do {                                             \
        const int kb_ = (kt) * (BK * 2);                                         \
        async16((ab) + loff + kb_,      aD + ((buf) << 14));                     \
        async16((ab) + loff + RS + kb_, aD + ((buf) << 14) + 8192);              \
        async16((bb) + loff + kb_,      bD + ((buf) << 14));                     \
        async16((bb) + loff + RS + kb_, bD + ((buf) << 14) + 8192);              \
    } while (0)

    STAGE0(aCb, bCb, 0, 0); STAGE0(aCb, bCb, 1, 1); STAGE0(aCb, bCb, 2, 2);
    asm volatile("s_waitcnt vmcnt(8)" ::: "memory");   // tile 0 landed (mine)
    __builtin_amdgcn_s_barrier();                      // tile 0 landed (all)
    asm volatile("" ::: "memory");
#pragma unroll
    for (int j = 0; j < 4; j++) fb[j] = *(const bf16x8*)(lds + boff + j * 1024);
#pragma unroll
    for (int i = 0; i < 8; i++) fa[i] = *(const bf16x8*)(lds + aoff + i * 1024);

    for (;;) {
        // next tile (dummy = self for the last: dead prefetch, uniform vmcnt)
        const int nidx  = idx + 32;
        const int ntile = (nidx < CHUNK) ? (xcd * CHUNK + nidx) : tile;
        const int nbm = ntile / NBN, nbn = ntile - nbm * NBN;
        const char* aNb = (const char*)A + (size_t)nbm * BM * K_DIM * 2;
        const char* bNb = (const char*)B + (size_t)nbn * BN * K_DIM * 2;

        // K loop: bodies 0..123 stage current tile (skt=kt+3 <= 126);
        // tail bodies 124..127 stage 127 then next-tile k0,k1,k2 into slots 3,0,1,2.
        for (int kt = 0; kt < 124; kt += 2) {
            BODY(kt,     fa, fb, ga, gb, aCb, bCb, kt + 3);
            BODY(kt + 1, ga, gb, fa, fb, aCb, bCb, kt + 4);
        }
        BODY(124, fa, fb, ga, gb, aCb, bCb, 127);
        BODY(125, ga, gb, fa, fb, aNb, bNb, 0);
        BODY(126, fa, fb, ga, gb, aNb, bNb, 1);
        BODY(127, ga, gb, fa, fb, aNb, bNb, 2);
        // fa/fb now hold next tile's K-tile-0 fragments (read from slot 0)

        // ---- epilogue (nontemporal: C has zero reuse; keep B resident in L2/L3)
        {
            const int gcol = bn * BN + wn * 64 + l16;
            float bvals[4];
#pragma unroll
            for (int j = 0; j < 4; j++) bvals[j] = bias[gcol + j * 16];
#pragma unroll
            for (int i = 0; i < 8; i++) {
                const int grow0 = bm * BM + wm * 128 + i * 16 + quad * 4;
#pragma unroll
                for (int r = 0; r < 4; r++) {
                    float* orow = out + (size_t)(grow0 + r) * N_DIM + gcol;
#pragma unroll
                    for (int j = 0; j < 4; j++)
                        __builtin_nontemporal_store(acc[i][j][r] * scale + bvals[j],
                                                    orow + j * 16);
                }
            }
#pragma unroll
            for (int i = 0; i < 8; i++)
#pragma unroll
                for (int j = 0; j < 4; j++)
                    acc[i][j] = (f32x4){0.f, 0.f, 0.f, 0.f};
        }

        if (nidx >= CHUNK) break;
        idx = nidx; tile = ntile; bm = nbm; bn = nbn; aCb = aNb; bCb = bNb;
    }
#undef STAGE0
}

// correctness fallback if ws is too small (should not trigger: needs ~157 MB)
__global__ __launch_bounds__(256) void naive_kernel(
    const float* __restrict__ x, const int* __restrict__ w8,
    const float* __restrict__ scale_p, const float* __restrict__ bias,
    float* __restrict__ out)
{
    size_t idx = (size_t)blockIdx.x * 256 + threadIdx.x;
    if (idx >= (size_t)M_DIM * N_DIM) return;
    int n = (int)(idx % N_DIM);
    size_t m = idx / N_DIM;
    const float* xr = x + m * K_DIM;
    const int* wr = w8 + (size_t)n * K_DIM;
    float acc = 0.f;
    for (int k = 0; k < K_DIM; k++) acc += xr[k] * (float)wr[k];
    out[idx] = acc * (*scale_p) + bias[n];
}

extern "C" void kernel_launch(void* const* d_in, const int* in_sizes, int n_in,
                              void* d_out, int out_size, void* d_ws, size_t ws_size,
                              hipStream_t stream) {
    const float* x     = (const float*)d_in[0];
    const int*   w8    = (const int*)d_in[1];
    const float* scale = (const float*)d_in[2];
    const float* bias  = (const float*)d_in[3];
    float* out = (float*)d_out;

    const size_t a_bytes = (size_t)M_DIM * K_DIM * 2;   // 67,108,864
    const size_t b_bytes = (size_t)N_DIM * K_DIM * 2;   // 90,177,536

    if (ws_size >= a_bytes + b_bytes) {
        unsigned short* a_bf = (unsigned short*)d_ws;
        unsigned short* b_bf = (unsigned short*)((char*)d_ws + a_bytes);
        cvt_fused_kernel<<<4096, 256, 0, stream>>>(x, w8, a_bf, b_bf);
        gemm_persistent<<<256, 512, 0, stream>>>(a_bf, b_bf, scale, bias, out);
    } else {
        size_t total = (size_t)M_DIM * N_DIM;
        naive_kernel<<<(unsigned)((total + 255) / 256), 256, 0, stream>>>(
            x, w8, scale, bias, out);
    }
}